// Round 6
// baseline (139.077 us; speedup 1.0000x reference)
//
#include <hip/hip_runtime.h>

#define HW 4096

typedef float f32x4 __attribute__((ext_vector_type(4)));
typedef __bf16 bf16x8 __attribute__((ext_vector_type(8)));
typedef unsigned short u16x8 __attribute__((ext_vector_type(8)));
typedef unsigned short u16x16 __attribute__((ext_vector_type(16)));

union F8 { bf16x8 v; unsigned long long q[2]; unsigned short u[8]; __bf16 h[8]; };

__device__ inline unsigned short f2bf(float f) {
    unsigned int u = __builtin_bit_cast(unsigned int, f);
    u += 0x7fffu + ((u >> 16) & 1u);   // RNE
    return (unsigned short)(u >> 16);
}
__device__ inline float bf2f(unsigned short h) {
    unsigned int u = ((unsigned int)h) << 16;
    return __builtin_bit_cast(float, u);
}
__device__ inline bf16x8 frag_lo(const unsigned short* p) {
    F8 f; f.q[0] = *(const unsigned long long*)p; f.q[1] = 0ull; return f.v;
}

#define MFMA16(a,b,c) __builtin_amdgcn_mfma_f32_16x16x32_bf16(a, b, c, 0, 0, 0)
#define EXP2(x) __builtin_amdgcn_exp2f(x)

// ---------------------------------------------------------------------------
// Kernel 1: projections, W staged in LDS (r5 win, kept). NEW: (a) Wq/bq
// pre-scaled by A2 = log2e/sqrt(8) so attn's exp arg needs no fma; (b) q/k
// written as one 32B vector store per pixel (rg0 w0/w1 own all 8 rows).
// v -> fragment-major vt (unchanged, matches attn B-frag slots).
// grid 1024 = 4 b x 64 ntiles x 4 rowgroups; block 256.
// ---------------------------------------------------------------------------
__global__ __launch_bounds__(256, 4) void proj_kernel(
    const float* __restrict__ x,
    const float* __restrict__ Wq, const float* __restrict__ bq,
    const float* __restrict__ Wk, const float* __restrict__ bk,
    const float* __restrict__ Wv, const float* __restrict__ bv,
    unsigned short* __restrict__ qbuf, unsigned short* __restrict__ kbuf,
    unsigned short* __restrict__ vtbuf)
{
    const float A2 = 0.51006977f;      // log2(e)/sqrt(8), folded into q
    __shared__ float ldsW[80][64];     // rows: 0..7 Wq*A2, 8..15 Wk, 16..79 Wv
    __shared__ float ldsB[80];

    const int blk   = blockIdx.x;
    const int b     = blk >> 8;
    const int rest  = blk & 255;
    const int ntile = rest >> 2;
    const int rg    = rest & 3;
    const int tid   = threadIdx.x;
    const int w     = tid >> 6;
    const int lane  = tid & 63;
    const int n     = ntile * 64 + lane;

#pragma unroll
    for (int kk = 0; kk < 5; ++kk) {
        const int idx = tid + kk * 256;          // f32x4 slot 0..1279
        const int r   = idx >> 4;                // row 0..79
        const int c   = (idx & 15) << 2;         // col 0,4,..,60
        f32x4 val;
        if (r < 8) { val = *(const f32x4*)(Wq + r * 64 + c); val *= A2; }
        else if (r < 16) val = *(const f32x4*)(Wk + (r - 8) * 64 + c);
        else             val = *(const f32x4*)(Wv + (r - 16) * 64 + c);
        *(f32x4*)(&ldsW[r][c]) = val;
    }
    if (tid < 80) {
        float bb = (tid < 8) ? bq[tid] * A2
                 : (tid < 16) ? bk[tid - 8] : bv[tid - 16];
        ldsB[tid] = bb;
    }
    __syncthreads();

    const float* xb = x + (size_t)b * 64 * HW + n;
    float xv[64];
#pragma unroll
    for (int c = 0; c < 64; ++c) xv[c] = xb[c * HW];

    auto rowdot = [&](int row) -> float {
        const float* wr = &ldsW[row][0];
        float a0 = 0.f, a1 = 0.f, a2 = 0.f, a3 = 0.f;
#pragma unroll
        for (int c4 = 0; c4 < 16; ++c4) {
            f32x4 wv = *(const f32x4*)(wr + c4 * 4);   // uniform broadcast
            a0 = fmaf(wv[0], xv[c4*4+0], a0);
            a1 = fmaf(wv[1], xv[c4*4+1], a1);
            a2 = fmaf(wv[2], xv[c4*4+2], a2);
            a3 = fmaf(wv[3], xv[c4*4+3], a3);
        }
        return (a0 + a1) + (a2 + a3) + ldsB[row];
    };

    // fragment-major v address for pixel n (within one c-row of one batch)
    const int vaddr = ((n >> 5) << 5) + (((n >> 2) & 3) << 3)
                    + (n & 3) + (((n >> 4) & 1) << 2);
    unsigned short* vB = vtbuf + (size_t)b * 64 * HW + vaddr;

    if (rg == 0) {
        if (w == 0) {                    // all 8 q rows -> one 32B store
            u16x16 qv;
#pragma unroll
            for (int d = 0; d < 8; ++d) qv[d] = f2bf(rowdot(d));
#pragma unroll
            for (int d = 8; d < 16; ++d) qv[d] = 0;
            *(u16x16*)(qbuf + (size_t)(b * HW + n) * 16) = qv;
        } else if (w == 1) {             // all 8 k rows
            u16x16 kv;
#pragma unroll
            for (int d = 0; d < 8; ++d) kv[d] = f2bf(rowdot(8 + d));
#pragma unroll
            for (int d = 8; d < 16; ++d) kv[d] = 0;
            *(u16x16*)(kbuf + (size_t)(b * HW + n) * 16) = kv;
        } else {                         // v c0..3 (2 per wave)
#pragma unroll
            for (int cc = 0; cc < 2; ++cc) {
                const int c = (w - 2) * 2 + cc;
                vB[(size_t)c * HW] = f2bf(rowdot(16 + c));
            }
        }
    } else {                             // v c4..63, 5 per wave
#pragma unroll
        for (int rr = 0; rr < 5; ++rr) {
            const int c = 4 + (rg - 1) * 20 + w * 5 + rr;
            vB[(size_t)c * HW] = f2bf(rowdot(16 + c));
        }
    }
}

// ---------------------------------------------------------------------------
// Kernel 2: attention + skip. Softmax with NO shift: p = exp2(s) where the
// log2e/sqrt(8) scale is pre-folded into Q; the uniform 2^(-max) factor
// cancels in O/L (exact; s*A2 bounded ~ +-20 -> f32 safe).
// Swapped QK^T: S^T = mfma(K,Q); C-frag (col=ln=q, row=4g+r=m) doubles as
// the PV A-frag (operand-slot bijection => layout-safe). Row-sums L via a
// ones-B MFMA (same C layout as O, no shuffles).
// Wave = 64 q (4 subtiles) x 32 c (c-half) x 512 m (16 iters).
// Block = 8 waves = 8 m-slices; merge in LDS. grid 512 = qt(64) x slot(8),
// slot = (b, c-half) pinned per XCD -> ~1.3 MB L2 working set per XCD.
// (512,2): 2 blocks/CU = 16 waves/CU, VGPR cap 128 (need ~110).
// ---------------------------------------------------------------------------
__global__ __launch_bounds__(512, 2) void attn_kernel(
    const unsigned short* __restrict__ qbuf,
    const unsigned short* __restrict__ kbuf,
    const unsigned short* __restrict__ vtbuf,
    const float* __restrict__ x,
    const float* __restrict__ gamma,
    float* __restrict__ out)
{
    const int blk  = blockIdx.x;
    const int slot = blk & 7;              // XCD slot = (b, c-half)
    const int qt   = blk >> 3;             // 0..63
    const int b    = slot >> 1;
    const int ct   = slot & 1;
    const int nb   = qt * 64;
    const int c0   = ct * 32;
    const int tid  = threadIdx.x;
    const int w    = tid >> 6;             // 0..7 = m-slice
    const int lane = tid & 63;
    const int g    = lane >> 4;
    const int ln   = lane & 15;

    __shared__ unsigned short ldsO[8][64][34];   // bf16 partials, padded
    __shared__ float ldsL[8][64];

    // Q B-frags for 4 query subtiles (q = nb + 16i + ln)
    bf16x8 qf[4];
#pragma unroll
    for (int i = 0; i < 4; ++i)
        qf[i] = frag_lo(qbuf + (size_t)(b * HW + nb + 16 * i + ln) * 16 + 4 * g);

    F8 onesu;
#pragma unroll
    for (int e = 0; e < 8; ++e) onesu.u[e] = 0x3F80;   // bf16 1.0
    const bf16x8 ones = onesu.v;

    f32x4 o[4][2], ol[4];
#pragma unroll
    for (int i = 0; i < 4; ++i) {
        o[i][0] = (f32x4){0,0,0,0};
        o[i][1] = (f32x4){0,0,0,0};
        ol[i]   = (f32x4){0,0,0,0};
    }

    const int mq = w * 512;                // this wave's m-slice
    const unsigned short* kb = kbuf + (size_t)(b * HW + mq + ln) * 16 + 4 * g;
    const unsigned short* vb = vtbuf + (size_t)b * 64 * HW
                             + (size_t)(c0 + ln) * HW + mq + 8 * g;

#pragma unroll 4
    for (int ch = 0; ch < 16; ++ch) {
        const unsigned short* kp = kb + ch * 512;   // 32 K-rows x 16 ushorts
        bf16x8 kf0 = frag_lo(kp);
        bf16x8 kf1 = frag_lo(kp + 256);
        const unsigned short* vp = vb + ch * 32;
        bf16x8 vf0 = *(const bf16x8*)(vp);           // c rows c0+ln
        bf16x8 vf1 = *(const bf16x8*)(vp + 16 * HW); // c rows c0+16+ln

        F8 pa[4];
        const f32x4 z = {0.f, 0.f, 0.f, 0.f};
#pragma unroll
        for (int i = 0; i < 4; ++i) {
            f32x4 s0 = MFMA16(kf0, qf[i], z);
            f32x4 s1 = MFMA16(kf1, qf[i], z);
#pragma unroll
            for (int r = 0; r < 4; ++r) {
                pa[i].h[r]     = (__bf16)EXP2(s0[r]);
                pa[i].h[r + 4] = (__bf16)EXP2(s1[r]);
            }
        }
        __builtin_amdgcn_s_setprio(1);
#pragma unroll
        for (int i = 0; i < 4; ++i) {
            o[i][0] = MFMA16(pa[i].v, vf0, o[i][0]);
            o[i][1] = MFMA16(pa[i].v, vf1, o[i][1]);
            ol[i]   = MFMA16(pa[i].v, ones, ol[i]);
        }
        __builtin_amdgcn_s_setprio(0);
    }

    // stash partials: q = 16i + 4g + r, c-col = ln (+16)
#pragma unroll
    for (int i = 0; i < 4; ++i) {
#pragma unroll
        for (int r = 0; r < 4; ++r) {
            ldsO[w][16 * i + 4 * g + r][ln]      = f2bf(o[i][0][r]);
            ldsO[w][16 * i + 4 * g + r][16 + ln] = f2bf(o[i][1][r]);
        }
    }
    if (ln == 0) {
#pragma unroll
        for (int i = 0; i < 4; ++i)
#pragma unroll
            for (int r = 0; r < 4; ++r)
                ldsL[w][16 * i + 4 * g + r] = ol[i][r];
    }
    __syncthreads();

    // merge 8 m-slice partials; fused epilogue out = gamma*(O/L) + x
    const int q  = tid & 63;
    const int c8 = tid >> 6;               // 0..7
    float L = 0.f;
#pragma unroll
    for (int wv = 0; wv < 8; ++wv) L += ldsL[wv][q];
    const float inv = 1.0f / L;
    const float gm  = gamma[0];
#pragma unroll
    for (int j = 0; j < 4; ++j) {
        const int c = c8 + 8 * j;          // 0..31
        float Ov = 0.f;
#pragma unroll
        for (int wv = 0; wv < 8; ++wv) Ov += bf2f(ldsO[wv][q][c]);
        const size_t idx = (size_t)(b * 64 + c0 + c) * HW + nb + q;
        out[idx] = fmaf(gm, Ov * inv, x[idx]);
    }
}

extern "C" void kernel_launch(void* const* d_in, const int* in_sizes, int n_in,
                              void* d_out, int out_size, void* d_ws, size_t ws_size,
                              hipStream_t stream) {
    const float* x  = (const float*)d_in[0];
    const float* Wq = (const float*)d_in[1];
    const float* bq = (const float*)d_in[2];
    const float* Wk = (const float*)d_in[3];
    const float* bk = (const float*)d_in[4];
    const float* Wv = (const float*)d_in[5];
    const float* bv = (const float*)d_in[6];
    const float* gm = (const float*)d_in[7];

    // ws layout: qbuf 512KB | kbuf 512KB | vtbuf 2MB  (total 3MB)
    unsigned short* qbuf  = (unsigned short*)d_ws;
    unsigned short* kbuf  = qbuf + 4 * HW * 16;
    unsigned short* vtbuf = kbuf + 4 * HW * 16;
    float* out = (float*)d_out;

    proj_kernel<<<1024, 256, 0, stream>>>(x, Wq, bq, Wk, bk, Wv, bv,
                                          qbuf, kbuf, vtbuf);
    attn_kernel<<<512, 512, 0, stream>>>(qbuf, kbuf, vtbuf, x, gm, out);
}

// Round 7
// 38.587 us; speedup vs baseline: 3.6042x; 3.6042x over previous
//
#include <hip/hip_runtime.h>

#define HW 4096

typedef float f32x4 __attribute__((ext_vector_type(4)));
typedef __bf16 bf16x8 __attribute__((ext_vector_type(8)));
typedef unsigned short u16x8 __attribute__((ext_vector_type(8)));

union F8 { bf16x8 v; unsigned long long q[2]; unsigned short u[8]; __bf16 h[8]; };

__device__ inline unsigned short f2bf(float f) {
    unsigned int u = __builtin_bit_cast(unsigned int, f);
    u += 0x7fffu + ((u >> 16) & 1u);   // RNE
    return (unsigned short)(u >> 16);
}
__device__ inline float bf2f(unsigned short h) {
    unsigned int u = ((unsigned int)h) << 16;
    return __builtin_bit_cast(float, u);
}
__device__ inline bf16x8 frag_lo(const unsigned short* p) {
    F8 f; f.q[0] = *(const unsigned long long*)p; f.q[1] = 0ull; return f.v;
}

#define MFMA16(a,b,c) __builtin_amdgcn_mfma_f32_16x16x32_bf16(a, b, c, 0, 0, 0)
#define EXP2(x) __builtin_amdgcn_exp2f(x)

// ---------------------------------------------------------------------------
// Kernel 1: projections — r5 structure restored (5 wave-uniform rows/thread,
// scalar q/k stores; the r6 8-row u16x16 variant spilled: VGPR capped 64 vs
// ~100 needed -> 312MB scratch traffic, 135us). Changes vs r5:
//   (a) Wq/bq pre-scaled by A2 = log2e/sqrt(8)  (attn depends on this)
//   (b) __launch_bounds__(256, 2): VGPR cap 256 so xv[64]+acc never spills.
// W staged in LDS, read as wave-uniform broadcasts.
// grid 1024 = 4 b x 64 ntiles x 4 rowgroups; block 256.
// ---------------------------------------------------------------------------
__global__ __launch_bounds__(256, 2) void proj_kernel(
    const float* __restrict__ x,
    const float* __restrict__ Wq, const float* __restrict__ bq,
    const float* __restrict__ Wk, const float* __restrict__ bk,
    const float* __restrict__ Wv, const float* __restrict__ bv,
    unsigned short* __restrict__ qbuf, unsigned short* __restrict__ kbuf,
    unsigned short* __restrict__ vtbuf)
{
    const float A2 = 0.51006977f;      // log2(e)/sqrt(8), folded into q
    __shared__ float ldsW[80][64];     // rows: 0..7 Wq*A2, 8..15 Wk, 16..79 Wv
    __shared__ float ldsB[80];

    const int blk   = blockIdx.x;
    const int b     = blk >> 8;
    const int rest  = blk & 255;
    const int ntile = rest >> 2;
    const int rg    = rest & 3;
    const int tid   = threadIdx.x;
    const int w     = tid >> 6;
    const int lane  = tid & 63;
    const int n     = ntile * 64 + lane;

    // stage W: 5120 floats = 1280 f32x4, 256 threads x 5
#pragma unroll
    for (int kk = 0; kk < 5; ++kk) {
        const int idx = tid + kk * 256;          // f32x4 slot 0..1279
        const int r   = idx >> 4;                // row 0..79
        const int c   = (idx & 15) << 2;         // col 0,4,..,60
        f32x4 val;
        if (r < 8) { val = *(const f32x4*)(Wq + r * 64 + c); val *= A2; }
        else if (r < 16) val = *(const f32x4*)(Wk + (r - 8) * 64 + c);
        else             val = *(const f32x4*)(Wv + (r - 16) * 64 + c);
        *(f32x4*)(&ldsW[r][c]) = val;
    }
    if (tid < 80) {
        float bb = (tid < 8) ? bq[tid] * A2
                 : (tid < 16) ? bk[tid - 8] : bv[tid - 16];
        ldsB[tid] = bb;
    }
    __syncthreads();

    const float* xb = x + (size_t)b * 64 * HW + n;
    float xv[64];
#pragma unroll
    for (int c = 0; c < 64; ++c) xv[c] = xb[c * HW];

    auto rowdot = [&](int row) -> float {
        const float* wr = &ldsW[row][0];
        float a0 = 0.f, a1 = 0.f, a2 = 0.f, a3 = 0.f;
#pragma unroll
        for (int c4 = 0; c4 < 16; ++c4) {
            f32x4 wv = *(const f32x4*)(wr + c4 * 4);   // uniform broadcast
            a0 = fmaf(wv[0], xv[c4*4+0], a0);
            a1 = fmaf(wv[1], xv[c4*4+1], a1);
            a2 = fmaf(wv[2], xv[c4*4+2], a2);
            a3 = fmaf(wv[3], xv[c4*4+3], a3);
        }
        return (a0 + a1) + (a2 + a3) + ldsB[row];
    };

    // fragment-major v address for pixel n (within one c-row of one batch)
    const int vaddr = ((n >> 5) << 5) + (((n >> 2) & 3) << 3)
                    + (n & 3) + (((n >> 4) & 1) << 2);

    const int r0 = rg * 20 + w * 5;
#pragma unroll
    for (int rr = 0; rr < 5; ++rr) {
        const int row = r0 + rr;            // wave-uniform
        float val = rowdot(row);
        if (row < 8) {
            unsigned short* qr = qbuf + (size_t)(b * HW + n) * 16;
            qr[row] = f2bf(val);
            qr[row + 8] = 0;
        } else if (row < 16) {
            unsigned short* kr = kbuf + (size_t)(b * HW + n) * 16;
            kr[row - 8] = f2bf(val);
            kr[row] = 0;
        } else {
            vtbuf[(size_t)b * 64 * HW + (size_t)(row - 16) * HW + vaddr] = f2bf(val);
        }
    }
}

// ---------------------------------------------------------------------------
// Kernel 2: attention + skip (UNCHANGED from r6 — measured ~4us, verified).
// Softmax with NO shift: p = exp2(s), scale pre-folded into Q; uniform
// 2^(-max) cancels in O/L. Swapped QK^T: S^T = mfma(K,Q); C-frag doubles as
// PV A-frag. Row-sums L via ones-B MFMA. Wave = 64q x 32c x 512m.
// grid 512 = qt(64) x slot(8); slot=(b,c-half) pinned per XCD.
// ---------------------------------------------------------------------------
__global__ __launch_bounds__(512, 2) void attn_kernel(
    const unsigned short* __restrict__ qbuf,
    const unsigned short* __restrict__ kbuf,
    const unsigned short* __restrict__ vtbuf,
    const float* __restrict__ x,
    const float* __restrict__ gamma,
    float* __restrict__ out)
{
    const int blk  = blockIdx.x;
    const int slot = blk & 7;              // XCD slot = (b, c-half)
    const int qt   = blk >> 3;             // 0..63
    const int b    = slot >> 1;
    const int ct   = slot & 1;
    const int nb   = qt * 64;
    const int c0   = ct * 32;
    const int tid  = threadIdx.x;
    const int w    = tid >> 6;             // 0..7 = m-slice
    const int lane = tid & 63;
    const int g    = lane >> 4;
    const int ln   = lane & 15;

    __shared__ unsigned short ldsO[8][64][34];   // bf16 partials, padded
    __shared__ float ldsL[8][64];

    // Q B-frags for 4 query subtiles (q = nb + 16i + ln)
    bf16x8 qf[4];
#pragma unroll
    for (int i = 0; i < 4; ++i)
        qf[i] = frag_lo(qbuf + (size_t)(b * HW + nb + 16 * i + ln) * 16 + 4 * g);

    F8 onesu;
#pragma unroll
    for (int e = 0; e < 8; ++e) onesu.u[e] = 0x3F80;   // bf16 1.0
    const bf16x8 ones = onesu.v;

    f32x4 o[4][2], ol[4];
#pragma unroll
    for (int i = 0; i < 4; ++i) {
        o[i][0] = (f32x4){0,0,0,0};
        o[i][1] = (f32x4){0,0,0,0};
        ol[i]   = (f32x4){0,0,0,0};
    }

    const int mq = w * 512;                // this wave's m-slice
    const unsigned short* kb = kbuf + (size_t)(b * HW + mq + ln) * 16 + 4 * g;
    const unsigned short* vb = vtbuf + (size_t)b * 64 * HW
                             + (size_t)(c0 + ln) * HW + mq + 8 * g;

#pragma unroll 4
    for (int ch = 0; ch < 16; ++ch) {
        const unsigned short* kp = kb + ch * 512;   // 32 K-rows x 16 ushorts
        bf16x8 kf0 = frag_lo(kp);
        bf16x8 kf1 = frag_lo(kp + 256);
        const unsigned short* vp = vb + ch * 32;
        bf16x8 vf0 = *(const bf16x8*)(vp);           // c rows c0+ln
        bf16x8 vf1 = *(const bf16x8*)(vp + 16 * HW); // c rows c0+16+ln

        F8 pa[4];
        const f32x4 z = {0.f, 0.f, 0.f, 0.f};
#pragma unroll
        for (int i = 0; i < 4; ++i) {
            f32x4 s0 = MFMA16(kf0, qf[i], z);
            f32x4 s1 = MFMA16(kf1, qf[i], z);
#pragma unroll
            for (int r = 0; r < 4; ++r) {
                pa[i].h[r]     = (__bf16)EXP2(s0[r]);
                pa[i].h[r + 4] = (__bf16)EXP2(s1[r]);
            }
        }
        __builtin_amdgcn_s_setprio(1);
#pragma unroll
        for (int i = 0; i < 4; ++i) {
            o[i][0] = MFMA16(pa[i].v, vf0, o[i][0]);
            o[i][1] = MFMA16(pa[i].v, vf1, o[i][1]);
            ol[i]   = MFMA16(pa[i].v, ones, ol[i]);
        }
        __builtin_amdgcn_s_setprio(0);
    }

    // stash partials: q = 16i + 4g + r, c-col = ln (+16)
#pragma unroll
    for (int i = 0; i < 4; ++i) {
#pragma unroll
        for (int r = 0; r < 4; ++r) {
            ldsO[w][16 * i + 4 * g + r][ln]      = f2bf(o[i][0][r]);
            ldsO[w][16 * i + 4 * g + r][16 + ln] = f2bf(o[i][1][r]);
        }
    }
    if (ln == 0) {
#pragma unroll
        for (int i = 0; i < 4; ++i)
#pragma unroll
            for (int r = 0; r < 4; ++r)
                ldsL[w][16 * i + 4 * g + r] = ol[i][r];
    }
    __syncthreads();

    // merge 8 m-slice partials; fused epilogue out = gamma*(O/L) + x
    const int q  = tid & 63;
    const int c8 = tid >> 6;               // 0..7
    float L = 0.f;
#pragma unroll
    for (int wv = 0; wv < 8; ++wv) L += ldsL[wv][q];
    const float inv = 1.0f / L;
    const float gm  = gamma[0];
#pragma unroll
    for (int j = 0; j < 4; ++j) {
        const int c = c8 + 8 * j;          // 0..31
        float Ov = 0.f;
#pragma unroll
        for (int wv = 0; wv < 8; ++wv) Ov += bf2f(ldsO[wv][q][c]);
        const size_t idx = (size_t)(b * 64 + c0 + c) * HW + nb + q;
        out[idx] = fmaf(gm, Ov * inv, x[idx]);
    }
}

extern "C" void kernel_launch(void* const* d_in, const int* in_sizes, int n_in,
                              void* d_out, int out_size, void* d_ws, size_t ws_size,
                              hipStream_t stream) {
    const float* x  = (const float*)d_in[0];
    const float* Wq = (const float*)d_in[1];
    const float* bq = (const float*)d_in[2];
    const float* Wk = (const float*)d_in[3];
    const float* bk = (const float*)d_in[4];
    const float* Wv = (const float*)d_in[5];
    const float* bv = (const float*)d_in[6];
    const float* gm = (const float*)d_in[7];

    // ws layout: qbuf 512KB | kbuf 512KB | vtbuf 2MB  (total 3MB)
    unsigned short* qbuf  = (unsigned short*)d_ws;
    unsigned short* kbuf  = qbuf + 4 * HW * 16;
    unsigned short* vtbuf = kbuf + 4 * HW * 16;
    float* out = (float*)d_out;

    proj_kernel<<<1024, 256, 0, stream>>>(x, Wq, bq, Wk, bk, Wv, bv,
                                          qbuf, kbuf, vtbuf);
    attn_kernel<<<512, 512, 0, stream>>>(qbuf, kbuf, vtbuf, x, gm, out);
}